// Round 1
// baseline (254.497 us; speedup 1.0000x reference)
//
#include <hip/hip_runtime.h>
#include <stdint.h>

#define NA 98304
#define NT 1024
#define NC 21

// ws layout:
//   [0]   float cls_sum
//   [4]   int   n_pos
//   [8]   pad
//   [16]  u64 keys[NT]            (16 + 8192 bytes total zeroed each launch)
//   [16+8192] int minfo[NA]       (fully overwritten by k_match, no init needed)

__global__ __launch_bounds__(256) void k_match(
    const float4* __restrict__ anchors,
    const float4* __restrict__ tboxes,
    const int* __restrict__ tlabels,
    int* __restrict__ minfo,
    int* __restrict__ n_pos,
    unsigned long long* __restrict__ keys)
{
    __shared__ float4 s_t[NT];
    __shared__ int    s_l[NT];
    __shared__ float4 s_a[256];

    const int tid = threadIdx.x;
    for (int i = tid; i < NT; i += 256) {
        s_t[i] = tboxes[i];
        s_l[i] = tlabels[i];
    }
    const int a = blockIdx.x * 256 + tid;
    const float4 ab = anchors[a];
    s_a[tid] = ab;
    __syncthreads();

    // ---- phase 1: anchor-side max/argmax over all targets ----
    const float area_a = (ab.z - ab.x) * (ab.w - ab.y);
    float bi = 0.f, bu = 1.f;   // best (inter, union); init => iou 0, idx 0
    int bidx = 0;
    #pragma unroll 4
    for (int t = 0; t < NT; ++t) {
        const float4 tb = s_t[t];
        const float lx = fmaxf(ab.x, tb.x);
        const float ly = fmaxf(ab.y, tb.y);
        const float rx = fminf(ab.z, tb.z);
        const float ry = fminf(ab.w, tb.w);
        const float w  = fmaxf(rx - lx, 0.f);
        const float h  = fmaxf(ry - ly, 0.f);
        const float inter = w * h;
        const float uni = area_a + (tb.z - tb.x) * (tb.w - tb.y) - inter;
        // iou_t > iou_best  <=>  inter*bu > bi*uni  (both unions > 0)
        const bool gt = inter * bu > bi * uni;
        bi   = gt ? inter : bi;
        bu   = gt ? uni   : bu;
        bidx = gt ? t     : bidx;
    }
    const bool pos = (2.f * bi >= bu);   // max_iou >= 0.5
    minfo[a] = pos ? s_l[bidx] : -1;
    if (pos) atomicAdd(n_pos, 1);        // compiler wave-coalesces

    // ---- phase 2: target-side max/argmax over this block's 256 anchors ----
    #pragma unroll
    for (int j = 0; j < 4; ++j) {
        const int t = tid + 256 * j;
        const float4 tb = s_t[t];
        const float area_t = (tb.z - tb.x) * (tb.w - tb.y);
        float ci = 0.f, cu = 1.f;
        int cidx = 0;
        #pragma unroll 4
        for (int k = 0; k < 256; ++k) {
            const float4 qb = s_a[k];
            const float lx = fmaxf(qb.x, tb.x);
            const float ly = fmaxf(qb.y, tb.y);
            const float rx = fminf(qb.z, tb.z);
            const float ry = fminf(qb.w, tb.w);
            const float w  = fmaxf(rx - lx, 0.f);
            const float h  = fmaxf(ry - ly, 0.f);
            const float inter = w * h;
            const float uni = area_t + (qb.z - qb.x) * (qb.w - qb.y) - inter;
            const bool gt = inter * cu > ci * uni;
            ci   = gt ? inter : ci;
            cu   = gt ? uni   : cu;
            cidx = gt ? k     : cidx;
        }
        if (2.f * ci >= cu) {   // only candidates that can set t_mask matter
            const float iou = ci / cu;   // precise div, rare path
            const unsigned int ga = blockIdx.x * 256 + (unsigned int)cidx;
            const unsigned long long key =
                ((unsigned long long)__float_as_uint(iou) << 32) |
                (unsigned long long)(0xFFFFFFFFu - ga);   // smaller idx wins ties
            atomicMax(&keys[t], key);
        }
    }
}

__global__ __launch_bounds__(256) void k_cls(
    const float* __restrict__ preds,
    const int* __restrict__ minfo,
    float* __restrict__ cls_sum)
{
    float acc = 0.f;
    const int stride = gridDim.x * 256;
    for (int e = blockIdx.x * 256 + threadIdx.x; e < NA * NC; e += stride) {
        const int a = e / NC;
        const int c = e - a * NC;
        const int mi = minfo[a];
        const float x  = preds[e];
        const float t  = (mi == c) ? 1.f : 0.f;
        const float ax = fabsf(x);
        const float u  = __expf(-ax);
        // stable BCE-with-logits
        const float ce = fmaxf(x, 0.f) - x * t + __logf(1.f + u);
        // stable sigmoid
        const float p  = (x >= 0.f ? 1.f : u) / (1.f + u);
        const float pt = p * t + (1.f - p) * (1.f - t);
        const float at = 0.25f * t + 0.75f * (1.f - t);
        const float om = 1.f - pt;
        acc += at * om * om * ce;   // gamma=2 -> square
    }
    // block reduce: wave64 shuffle, then LDS across 4 waves
    for (int o = 32; o > 0; o >>= 1) acc += __shfl_down(acc, o);
    __shared__ float s_p[4];
    const int lane = threadIdx.x & 63, wid = threadIdx.x >> 6;
    if (lane == 0) s_p[wid] = acc;
    __syncthreads();
    if (threadIdx.x == 0)
        atomicAdd(cls_sum, s_p[0] + s_p[1] + s_p[2] + s_p[3]);
}

__device__ __forceinline__ float smooth_l1(float d) {
    const float ad = fabsf(d);
    return (ad < 1.f) ? 0.5f * d * d : ad - 0.5f;
}

__global__ __launch_bounds__(1024) void k_final(
    const float4* __restrict__ anchors,
    const float4* __restrict__ tboxes,
    const float4* __restrict__ bpreds,
    const unsigned long long* __restrict__ keys,
    const float* __restrict__ cls_sum,
    const int* __restrict__ n_pos,
    float* __restrict__ out)
{
    const int t = threadIdx.x;
    float s = 0.f, m = 0.f;
    const unsigned long long key = keys[t];
    if (key != 0ull) {   // nonzero iff some anchor had iou >= 0.5 with target t
        const unsigned int ga = 0xFFFFFFFFu - (unsigned int)(key & 0xFFFFFFFFull);
        const float4 tb = tboxes[t];
        const float4 ab = anchors[ga];
        const float4 pb = bpreds[ga];
        const float bw = tb.z - tb.x, bh = tb.w - tb.y;
        const float bcx = tb.x + 0.5f * bw, bcy = tb.y + 0.5f * bh;
        const float aw = ab.z - ab.x, ah = ab.w - ab.y;
        const float acx = ab.x + 0.5f * aw, acy = ab.y + 0.5f * ah;
        const float tx = (bcx - acx) / aw;
        const float ty = (bcy - acy) / ah;
        const float tw = logf(fmaxf(bw, 1e-8f) / aw);
        const float th = logf(fmaxf(bh, 1e-8f) / ah);
        s = smooth_l1(pb.x - tx) + smooth_l1(pb.y - ty) +
            smooth_l1(pb.z - tw) + smooth_l1(pb.w - th);
        m = 1.f;
    }
    for (int o = 32; o > 0; o >>= 1) {
        s += __shfl_down(s, o);
        m += __shfl_down(m, o);
    }
    __shared__ float s_s[16], s_m[16];
    const int lane = t & 63, wid = t >> 6;
    if (lane == 0) { s_s[wid] = s; s_m[wid] = m; }
    __syncthreads();
    if (t == 0) {
        float rs = 0.f, rm = 0.f;
        for (int i = 0; i < 16; ++i) { rs += s_s[i]; rm += s_m[i]; }
        const float cls = *cls_sum / (float)(*n_pos);
        const float reg = rs / (fmaxf(rm, 1.f) * 4.f);
        out[0] = cls + reg;
        out[1] = cls;
        out[2] = reg;
    }
}

extern "C" void kernel_launch(void* const* d_in, const int* in_sizes, int n_in,
                              void* d_out, int out_size, void* d_ws, size_t ws_size,
                              hipStream_t stream) {
    const float*  cls_preds = (const float*)d_in[0];
    const float4* bpreds    = (const float4*)d_in[1];
    const float4* anchors   = (const float4*)d_in[2];
    const float4* tboxes    = (const float4*)d_in[3];
    const int*    tlabels   = (const int*)d_in[4];

    char* ws = (char*)d_ws;
    float* cls_sum = (float*)(ws + 0);
    int*   n_pos   = (int*)(ws + 4);
    unsigned long long* keys = (unsigned long long*)(ws + 16);
    int*   minfo   = (int*)(ws + 16 + NT * 8);

    // zero accumulators + keys (ws is poisoned 0xAA before every launch)
    hipMemsetAsync(d_ws, 0, 16 + NT * 8, stream);

    k_match<<<NA / 256, 256, 0, stream>>>(anchors, tboxes, tlabels, minfo, n_pos, keys);
    k_cls<<<1024, 256, 0, stream>>>(cls_preds, minfo, cls_sum);
    k_final<<<1, 1024, 0, stream>>>(anchors, tboxes, bpreds, keys, cls_sum, n_pos,
                                    (float*)d_out);
}

// Round 2
// 210.293 us; speedup vs baseline: 1.2102x; 1.2102x over previous
//
#include <hip/hip_runtime.h>
#include <stdint.h>

#define NA 98304
#define NT 1024
#define NC 21
#define ACH 384          // anchor chunks of 256
#define TCH 4            // target chunks of 256

// ws layout:
//   [0]   float cls_sum
//   [4]   int   n_pos
//   [8]   int   done_cnt
//   [12]  pad
//   [16]        u64 tkeys[NT]    (8 KB)
//   [16+8192]   u64 akeys[NA]    (768 KB)
// memset covers [0, 16 + 8192 + NA*8)

__global__ __launch_bounds__(256) void k_match(
    const float4* __restrict__ anchors,
    const float4* __restrict__ tboxes,
    unsigned long long* __restrict__ akeys,
    unsigned long long* __restrict__ tkeys)
{
    __shared__ float4 s_t[256];
    __shared__ float4 s_a[256];

    const int tid = threadIdx.x;
    const int ac  = blockIdx.x;   // anchor chunk 0..383
    const int tc  = blockIdx.y;   // target chunk 0..3

    s_t[tid] = tboxes[tc * 256 + tid];
    const int a = ac * 256 + tid;
    const float4 ab = anchors[a];
    s_a[tid] = ab;
    __syncthreads();

    // ---- phase 1: this anchor vs the 256 targets of this chunk ----
    const float area_a = (ab.z - ab.x) * (ab.w - ab.y);
    float bi = 0.f, bu = 1.f;     // best (inter, union) => iou 0
    int bidx = 0;
    #pragma unroll 8
    for (int t = 0; t < 256; ++t) {
        const float4 tb = s_t[t];
        const float lx = fmaxf(ab.x, tb.x);
        const float ly = fmaxf(ab.y, tb.y);
        const float rx = fminf(ab.z, tb.z);
        const float ry = fminf(ab.w, tb.w);
        const float w  = fmaxf(rx - lx, 0.f);
        const float h  = fmaxf(ry - ly, 0.f);
        const float inter = w * h;
        const float uni = area_a + (tb.z - tb.x) * (tb.w - tb.y) - inter;
        const bool gt = inter * bu > bi * uni;   // exact cross-mult compare
        bi   = gt ? inter : bi;
        bu   = gt ? uni   : bu;
        bidx = gt ? t     : bidx;
    }
    if (2.f * bi >= bu) {                        // partial max >= 0.5: only these matter
        const float iou = bi / bu;               // same fp32 rounding as reference
        const unsigned int tg = (unsigned int)(tc * 256 + bidx);
        const unsigned long long key =
            ((unsigned long long)__float_as_uint(iou) << 32) |
            (unsigned long long)(0xFFFFFFFFu - tg);      // smaller t wins ties
        atomicMax(&akeys[a], key);
    }

    // ---- phase 2: this target vs the 256 anchors of this chunk ----
    const float4 tb = s_t[tid];
    const float area_t = (tb.z - tb.x) * (tb.w - tb.y);
    float ci = 0.f, cu = 1.f;
    int cidx = 0;
    #pragma unroll 8
    for (int k = 0; k < 256; ++k) {
        const float4 qb = s_a[k];
        const float lx = fmaxf(qb.x, tb.x);
        const float ly = fmaxf(qb.y, tb.y);
        const float rx = fminf(qb.z, tb.z);
        const float ry = fminf(qb.w, tb.w);
        const float w  = fmaxf(rx - lx, 0.f);
        const float h  = fmaxf(ry - ly, 0.f);
        const float inter = w * h;
        const float uni = area_t + (qb.z - qb.x) * (qb.w - qb.y) - inter;
        const bool gt = inter * cu > ci * uni;
        ci   = gt ? inter : ci;
        cu   = gt ? uni   : cu;
        cidx = gt ? k     : cidx;
    }
    if (2.f * ci >= cu) {
        const float iou = ci / cu;
        const unsigned int ga = (unsigned int)(ac * 256 + cidx);
        const unsigned long long key =
            ((unsigned long long)__float_as_uint(iou) << 32) |
            (unsigned long long)(0xFFFFFFFFu - ga);      // smaller anchor wins ties
        atomicMax(&tkeys[tc * 256 + tid], key);
    }
}

__device__ __forceinline__ float smooth_l1(float d) {
    const float ad = fabsf(d);
    return (ad < 1.f) ? 0.5f * d * d : ad - 0.5f;
}

// one block per 256 anchors; last-finishing block computes reg loss + writes out
__global__ __launch_bounds__(256) void k_cls_final(
    const float* __restrict__ preds,
    const int* __restrict__ tlabels,
    const float4* __restrict__ anchors,
    const float4* __restrict__ tboxes,
    const float4* __restrict__ bpreds,
    const unsigned long long* __restrict__ akeys,
    const unsigned long long* __restrict__ tkeys,
    float* __restrict__ cls_sum,
    int* __restrict__ n_pos,
    int* __restrict__ done_cnt,
    float* __restrict__ out)
{
    __shared__ int s_lab[256];
    __shared__ float s_red[8];
    __shared__ int s_flag;
    __shared__ float s_cls;
    __shared__ int s_np;

    const int tid = threadIdx.x;
    const int blk = blockIdx.x;
    const int a   = blk * 256 + tid;

    const unsigned long long akey = akeys[a];
    int lab = -1;
    if (akey != 0ull) {
        const unsigned int t = 0xFFFFFFFFu - (unsigned int)(akey & 0xFFFFFFFFull);
        lab = tlabels[t];
    }
    s_lab[tid] = lab;
    const unsigned long long bal = __ballot(akey != 0ull);
    if ((tid & 63) == 0) atomicAdd(n_pos, (int)__popcll(bal));
    __syncthreads();

    // focal loss over this block's 256 anchors x 21 classes (contiguous, coalesced)
    float acc = 0.f;
    const int base = blk * (256 * NC);
    for (int e = tid; e < 256 * NC; e += 256) {
        const int al = e / NC;            // magic-mul div
        const int c  = e - al * NC;
        const float x  = preds[base + e];
        const float t  = (s_lab[al] == c) ? 1.f : 0.f;
        const float ax = fabsf(x);
        const float u  = __expf(-ax);
        const float ce = fmaxf(x, 0.f) - x * t + __logf(1.f + u);
        const float p  = (x >= 0.f ? 1.f : u) / (1.f + u);
        const float pt = p * t + (1.f - p) * (1.f - t);
        const float at = 0.25f * t + 0.75f * (1.f - t);
        const float om = 1.f - pt;
        acc += at * om * om * ce;
    }
    for (int o = 32; o > 0; o >>= 1) acc += __shfl_down(acc, o);
    const int lane = tid & 63, wid = tid >> 6;
    if (lane == 0) s_red[wid] = acc;
    __syncthreads();
    if (tid == 0) {
        atomicAdd(cls_sum, s_red[0] + s_red[1] + s_red[2] + s_red[3]);
        __threadfence();
        const int old = atomicAdd(done_cnt, 1);
        s_flag = (old == (int)gridDim.x - 1);
    }
    __syncthreads();
    if (!s_flag) return;

    // ---- last block: regression loss + final combine ----
    if (tid == 0) {
        s_cls = atomicAdd(cls_sum, 0.f);  // coherent device-scope read
        s_np  = atomicAdd(n_pos, 0);
    }
    __syncthreads();

    float s = 0.f, m = 0.f;
    #pragma unroll
    for (int j = 0; j < 4; ++j) {
        const int t = tid + 256 * j;
        const unsigned long long key = tkeys[t];
        if (key != 0ull) {
            const unsigned int ga = 0xFFFFFFFFu - (unsigned int)(key & 0xFFFFFFFFull);
            const float4 tb = tboxes[t];
            const float4 abx = anchors[ga];
            const float4 pb = bpreds[ga];
            const float bw = tb.z - tb.x, bh = tb.w - tb.y;
            const float bcx = tb.x + 0.5f * bw, bcy = tb.y + 0.5f * bh;
            const float aw = abx.z - abx.x, ah = abx.w - abx.y;
            const float acx = abx.x + 0.5f * aw, acy = abx.y + 0.5f * ah;
            const float tx = (bcx - acx) / aw;
            const float ty = (bcy - acy) / ah;
            const float tw = logf(fmaxf(bw, 1e-8f) / aw);
            const float th = logf(fmaxf(bh, 1e-8f) / ah);
            s = smooth_l1(pb.x - tx) + smooth_l1(pb.y - ty) +
                smooth_l1(pb.z - tw) + smooth_l1(pb.w - th);
            m = 1.f;
        }
    }
    for (int o = 32; o > 0; o >>= 1) {
        s += __shfl_down(s, o);
        m += __shfl_down(m, o);
    }
    __syncthreads();          // s_red reuse
    if (lane == 0) { s_red[wid] = s; s_red[4 + wid] = m; }
    __syncthreads();
    if (tid == 0) {
        const float rs = s_red[0] + s_red[1] + s_red[2] + s_red[3];
        const float rm = s_red[4] + s_red[5] + s_red[6] + s_red[7];
        const float cls = s_cls / (float)s_np;
        const float reg = rs / (fmaxf(rm, 1.f) * 4.f);
        out[0] = cls + reg;
        out[1] = cls;
        out[2] = reg;
    }
}

extern "C" void kernel_launch(void* const* d_in, const int* in_sizes, int n_in,
                              void* d_out, int out_size, void* d_ws, size_t ws_size,
                              hipStream_t stream) {
    const float*  cls_preds = (const float*)d_in[0];
    const float4* bpreds    = (const float4*)d_in[1];
    const float4* anchors   = (const float4*)d_in[2];
    const float4* tboxes    = (const float4*)d_in[3];
    const int*    tlabels   = (const int*)d_in[4];

    char* ws = (char*)d_ws;
    float* cls_sum = (float*)(ws + 0);
    int*   n_pos   = (int*)(ws + 4);
    int*   done    = (int*)(ws + 8);
    unsigned long long* tkeys = (unsigned long long*)(ws + 16);
    unsigned long long* akeys = (unsigned long long*)(ws + 16 + NT * 8);

    hipMemsetAsync(d_ws, 0, 16 + NT * 8 + NA * 8, stream);

    k_match<<<dim3(ACH, TCH), 256, 0, stream>>>(anchors, tboxes, akeys, tkeys);
    k_cls_final<<<NA / 256, 256, 0, stream>>>(cls_preds, tlabels, anchors, tboxes,
                                              bpreds, akeys, tkeys,
                                              cls_sum, n_pos, done, (float*)d_out);
}